// Round 1
// baseline (9.638 us; speedup 1.0000x reference)
//
#include <hip/hip_runtime.h>

// GATPortfolioNet reduces to a CONSTANT output:
// project_weights = 10x { clip(w, 0.02, 0.25); w /= w.sum(); } with N=2000.
// For ANY probability vector w (N=2000 > 625 = 0.25/0.02^2):
//   - after clip, sum >= 0.02*N = 40, each element <= 0.25
//   - after renorm, each element <= 0.25/40 = 0.00625 < 0.02
//   - next clip flattens ALL elements to exactly 0.02f
//   - renorm -> uniform 0.02/(N*0.02) ~= 1/2000, a fixed point of the loop.
// Hence the reference output is the uniform vector independent of all inputs.
// fp32: 2000.0f*0.02f rounds to exactly 40.0f; 0.02f/40.0f = 4.9999999e-4,
// within ~1e-10 of any summation order the numpy reference uses (thr 1e-5).

__global__ void GATPortfolioNet_fill_uniform(float* __restrict__ out, int n, float v) {
    int i = blockIdx.x * blockDim.x + threadIdx.x;
    if (i < n) out[i] = v;
}

extern "C" void kernel_launch(void* const* d_in, const int* in_sizes, int n_in,
                              void* d_out, int out_size, void* d_ws, size_t ws_size,
                              hipStream_t stream) {
    (void)d_in; (void)in_sizes; (void)n_in; (void)d_ws; (void)ws_size;
    float* out = (float*)d_out;
    // Fixed point of the clip-renorm projection for N = out_size (=2000):
    // every element is 0.02 after the final clip; renormalize.
    const float v = 0.02f / ((float)out_size * 0.02f);
    int threads = 256;
    int blocks = (out_size + threads - 1) / threads;
    GATPortfolioNet_fill_uniform<<<blocks, threads, 0, stream>>>(out, out_size, v);
}